// Round 16
// baseline (2567.125 us; speedup 1.0000x reference)
//
#include <hip/hip_runtime.h>
#include <hip/hip_bf16.h>

// CentroidsFlowAD: out[row] = sqrt(max(||e||^2 + min_col(||c||^2 - 2 e.c), 0))
// rows = 32*3136 = 100352, cols = 2048 centroids, K = 1024.
//
// R16 FULL FUSION. R11/R14/R15 proved the split gemm is latency-structure
// bound at ~245us regardless of schedule (3 variants identical), and the
// e8 prep pass burns 78us writing+rereading a 98MB intermediate. One
// kernel per 64-row panel now does everything:
//   phase 1: read embeds fp32 ONCE (coalesced), cvt to fp8, write packed+
//            swizzled into LDS for the FULL K=1024 (64 KB), row sqnorms.
//   phase 2: sweep all 2048 centroids: 8 ct x 8 kt, B direct from L2
//            (c8t, verified R14/R15 layout), A from LDS, mfma_scale
//            16x16x128 (verified R9+), fold min per ct. ZERO barriers in
//            the loop -- waves fully independent; ILP + 16 waves/CU hide
//            latency (the thing 3-block TLP couldn't).
//   epilogue: cross-wave min + esq + sqrt -> out directly.
// Deleted: e8 (98MB round trip), esq, pmin, final_min, prep-embeds launch.
// Floors: HBM 392MB=62us | MFMA 90us | B-L2 3.1GB ~ under ceiling.
// 2 blocks/CU at launch_bounds(512,4)=128-reg unified budget; working set
// ~105 (acc32+runmin16+B16+temps16+addr~25) -- no spill (R9-R11 lesson).
// Prep: rowsq_fp8packT on centroids only (2 MB c8t + csq), ~3us.
// Fallback: round-1 fused kernel (proven, bf16).

typedef __bf16 bf16x8 __attribute__((ext_vector_type(8)));
typedef __bf16 bf16x4 __attribute__((ext_vector_type(4)));
typedef float f32x4 __attribute__((ext_vector_type(4)));
typedef int i32x4 __attribute__((ext_vector_type(4)));
typedef int i32x8 __attribute__((ext_vector_type(8)));

#define N_ROWS 100352
#define M_CENT 2048
#define D_K 1024

// fused fast-path geometry
#define BMF 64
#define NBLKF (N_ROWS / BMF)  // 1568
#define BPXF (NBLKF / 8)      // 196 per XCD

// fallback geometry (round-1, unchanged)
#define TM 128
#define TN 128
#define BK 64
#define NT_TILES (M_CENT / TN)  // 16
#define KT_STEPS (D_K / BK)     // 16

#define AS1 __attribute__((address_space(1)))
#define AS3 __attribute__((address_space(3)))

// ---- prep (centroids): fp32 -> TRANSPOSED fragment-major fp8 + sqnorm ----
// dst byte = ((seg*8 + s)*2048 + m)*16 + h*8 + j, s = ksp*4+g,
// k = 32*(2ksp+h) + 8g + j.  (verified R14/R15)
__global__ __launch_bounds__(256) void rowsq_fp8packT(const float* __restrict__ src,
                                                      unsigned char* __restrict__ dst,
                                                      float* __restrict__ sq) {
  const int m = blockIdx.x;   // centroid (becomes column)
  const int t = threadIdx.x;
  const float4 v = *reinterpret_cast<const float4*>(src + (size_t)m * D_K + t * 4);
  int pk = __builtin_amdgcn_cvt_pk_fp8_f32(v.x, v.y, 0, false);
  pk = __builtin_amdgcn_cvt_pk_fp8_f32(v.z, v.w, pk, true);
  const int k = t * 4;
  const int seg = k >> 7;
  const int ksi = (k >> 5) & 3;
  const int g = (k >> 3) & 3;
  const int j = k & 7;  // 0 or 4
  const int s = (ksi >> 1) * 4 + g;
  const size_t p = ((size_t)(seg * 8 + s) * 2048 + m) * 16 + (ksi & 1) * 8 + j;
  *reinterpret_cast<unsigned int*>(dst + p) = (unsigned int)pk;
  float ss = v.x * v.x + v.y * v.y + v.z * v.z + v.w * v.w;
  ss += __shfl_xor(ss, 1);
  ss += __shfl_xor(ss, 2);
  ss += __shfl_xor(ss, 4);
  ss += __shfl_xor(ss, 8);
  ss += __shfl_xor(ss, 16);
  ss += __shfl_xor(ss, 32);
  __shared__ float ws4[4];
  const int w = t >> 6, l = t & 63;
  if (l == 0) ws4[w] = ss;
  __syncthreads();
  if (t == 0) sq[m] = ws4[0] + ws4[1] + ws4[2] + ws4[3];
}

// ---- fused: 64-row panel, full-K A in LDS, all 2048 cols, out direct ----
// 512 threads = 8 waves; wave w owns cols (ct*256 + w*32 .. +32) per ct.
// LDS A layout (matches R5 pack + XOR swizzle, both sides):
//   byte = row*1024 + seg*128 + ((slot ^ (row&7))<<4) + h*8 + j.
__global__ __launch_bounds__(512, 4) void fused_mx(const float* __restrict__ embeds,
                                                   const unsigned char* __restrict__ c8t,
                                                   const float* __restrict__ csq,
                                                   float* __restrict__ out) {
  __shared__ __align__(16) char a8lds[65536];  // A[64 rows][1024 B] fp8
  __shared__ float sq4[64 * 4];                // per-row sqnorm quarters
  __shared__ float rowmin8[8][64];             // per-wave per-row min

  const int t = threadIdx.x;
  const int w = t >> 6;
  const int l = t & 63;
  const int g = l >> 4, lr = l & 15;

  // XCD swizzle: XCD k owns contiguous panels [196k, 196k+196). c8t (2 MB)
  // L2-resident per XCD; embeds streamed once.
  const int b = blockIdx.x;
  const int swz = (b & 7) * BPXF + (b >> 3);
  const long row0 = (long)swz * BMF;

  // ---------------- phase 1: embeds -> packed fp8 in LDS + sqnorms -------
  {
    const float4* src = reinterpret_cast<const float4*>(embeds + row0 * D_K);
#pragma unroll 4
    for (int i = 0; i < 32; ++i) {
      const int flat = i * 512 + t;  // float4 index within panel
      const int row = flat >> 8, idx = flat & 255;
      const float4 v = src[flat];
      int pk = __builtin_amdgcn_cvt_pk_fp8_f32(v.x, v.y, 0, false);
      pk = __builtin_amdgcn_cvt_pk_fp8_f32(v.z, v.w, pk, true);
      const int k = idx * 4;
      const int seg = k >> 7;
      const int ksi = (k >> 5) & 3;
      const int g2 = (k >> 3) & 3;
      const int j = k & 7;
      const int s = (ksi >> 1) * 4 + g2;
      const int byte =
          row * 1024 + seg * 128 + ((s ^ (row & 7)) << 4) + (ksi & 1) * 8 + j;
      *reinterpret_cast<int*>(a8lds + byte) = pk;
      float ss = v.x * v.x + v.y * v.y + v.z * v.z + v.w * v.w;
      ss += __shfl_xor(ss, 1);
      ss += __shfl_xor(ss, 2);
      ss += __shfl_xor(ss, 4);
      ss += __shfl_xor(ss, 8);
      ss += __shfl_xor(ss, 16);
      ss += __shfl_xor(ss, 32);
      // this wave-iteration covers exactly one quarter-row: row = 2i+(w>>2),
      // quad = w&3 (each (row,quad) written exactly once)
      if (l == 0) sq4[row * 4 + (w & 3)] = ss;
    }
  }
  __syncthreads();  // A + sq4 visible to all waves

  // ---------------- phase 2: sweep 2048 cols, no barriers ----------------
  float runmin[4][4];
#pragma unroll
  for (int m = 0; m < 4; ++m)
#pragma unroll
    for (int r = 0; r < 4; ++r) runmin[m][r] = 3.0e38f;

  // B pointers into c8t: frag (n, ksp) of (ct,kt) at
  //   ((kt*8 + ksp*4 + g)*2048 + col)*16, col = ct*256 + w*32 + n*16 + lr.
  const unsigned char* colp0 = c8t + ((size_t)g * 2048 + w * 32 + lr) * 16;
  const unsigned char* colp1 = colp0 + 16 * 16;  // n=1: +16 cols

  // A frag bases (row = m*16 + lr; row&7 == lr&7 -> m-invariant swizzle)
  const char* aB0 = a8lds + lr * 1024 + ((g ^ (lr & 7)) << 4);
  const char* aB1 = a8lds + lr * 1024 + (((4 + g) ^ (lr & 7)) << 4);

  for (int ct = 0; ct < 8; ++ct) {
    f32x4 acc[4][2];
#pragma unroll
    for (int m = 0; m < 4; ++m) {
      acc[m][0] = (f32x4){0.f, 0.f, 0.f, 0.f};
      acc[m][1] = (f32x4){0.f, 0.f, 0.f, 0.f};
    }
    const unsigned char* bp0 = colp0 + ct * 4096;
    const unsigned char* bp1 = colp1 + ct * 4096;
#pragma unroll
    for (int kt = 0; kt < 8; ++kt) {
      i32x8 b8[2];
      {
        const i32x4 lo0 = *reinterpret_cast<const i32x4*>(bp0 + (size_t)kt * 262144);
        const i32x4 hi0 =
            *reinterpret_cast<const i32x4*>(bp0 + (size_t)kt * 262144 + 131072);
        b8[0] = __builtin_shufflevector(lo0, hi0, 0, 1, 2, 3, 4, 5, 6, 7);
        const i32x4 lo1 = *reinterpret_cast<const i32x4*>(bp1 + (size_t)kt * 262144);
        const i32x4 hi1 =
            *reinterpret_cast<const i32x4*>(bp1 + (size_t)kt * 262144 + 131072);
        b8[1] = __builtin_shufflevector(lo1, hi1, 0, 1, 2, 3, 4, 5, 6, 7);
      }
#pragma unroll
      for (int m = 0; m < 4; ++m) {
        const i32x4 lo = *reinterpret_cast<const i32x4*>(aB0 + m * 16384 + kt * 128);
        const i32x4 hi = *reinterpret_cast<const i32x4*>(aB1 + m * 16384 + kt * 128);
        const i32x8 a8 = __builtin_shufflevector(lo, hi, 0, 1, 2, 3, 4, 5, 6, 7);
        acc[m][0] = __builtin_amdgcn_mfma_scale_f32_16x16x128_f8f6f4(
            a8, b8[0], acc[m][0], 0, 0, 0, 0x7F7F7F7F, 0, 0x7F7F7F7F);
        acc[m][1] = __builtin_amdgcn_mfma_scale_f32_16x16x128_f8f6f4(
            a8, b8[1], acc[m][1], 0, 0, 0, 0x7F7F7F7F, 0, 0x7F7F7F7F);
      }
    }
    // fold this ct's 32 cols into the running min
    const float cs0 = csq[ct * 256 + w * 32 + lr];
    const float cs1 = csq[ct * 256 + w * 32 + 16 + lr];
#pragma unroll
    for (int m = 0; m < 4; ++m)
#pragma unroll
      for (int r = 0; r < 4; ++r) {
        runmin[m][r] = fminf(runmin[m][r], cs0 - 2.0f * acc[m][0][r]);
        runmin[m][r] = fminf(runmin[m][r], cs1 - 2.0f * acc[m][1][r]);
      }
  }

  // lr-reduce (cols within the 16-lane group), then cross-wave via LDS
#pragma unroll
  for (int m = 0; m < 4; ++m)
#pragma unroll
    for (int r = 0; r < 4; ++r) {
      float v = runmin[m][r];
      v = fminf(v, __shfl_xor(v, 1));
      v = fminf(v, __shfl_xor(v, 2));
      v = fminf(v, __shfl_xor(v, 4));
      v = fminf(v, __shfl_xor(v, 8));
      runmin[m][r] = v;
    }
  if (lr == 0) {
#pragma unroll
    for (int m = 0; m < 4; ++m)
#pragma unroll
      for (int r = 0; r < 4; ++r) rowmin8[w][m * 16 + g * 4 + r] = runmin[m][r];
  }
  __syncthreads();
  if (t < BMF) {
    float v = rowmin8[0][t];
#pragma unroll
    for (int ww = 1; ww < 8; ++ww) v = fminf(v, rowmin8[ww][t]);
    const float es = sq4[t * 4] + sq4[t * 4 + 1] + sq4[t * 4 + 2] + sq4[t * 4 + 3];
    out[row0 + t] = sqrtf(fmaxf(es + v, 0.f));
  }
}

// ---- bf16 prep (fallback path) ----
__global__ __launch_bounds__(256) void rowsq_bf16(const float* __restrict__ src,
                                                  __bf16* __restrict__ dst,
                                                  float* __restrict__ sq) {
  const int m = blockIdx.x;
  const int t = threadIdx.x;
  const float4 v = *reinterpret_cast<const float4*>(src + (size_t)m * D_K + t * 4);
  bf16x4 o = {(__bf16)v.x, (__bf16)v.y, (__bf16)v.z, (__bf16)v.w};
  *reinterpret_cast<bf16x4*>(dst + (size_t)m * D_K + t * 4) = o;
  float ss = v.x * v.x + v.y * v.y + v.z * v.z + v.w * v.w;
  ss += __shfl_xor(ss, 1);
  ss += __shfl_xor(ss, 2);
  ss += __shfl_xor(ss, 4);
  ss += __shfl_xor(ss, 8);
  ss += __shfl_xor(ss, 16);
  ss += __shfl_xor(ss, 32);
  __shared__ float ws4[4];
  const int w = t >> 6, l = t & 63;
  if (l == 0) ws4[w] = ss;
  __syncthreads();
  if (t == 0) sq[m] = ws4[0] + ws4[1] + ws4[2] + ws4[3];
}

// =================== round-1 fallback (proven) ===================
template <bool WS>
__global__ __launch_bounds__(256, 2) void fused_min(const float* __restrict__ embeds,
                                                    const float* __restrict__ centf,
                                                    const __bf16* __restrict__ cbf,
                                                    const float* __restrict__ csq,
                                                    float* __restrict__ out) {
  __shared__ __align__(16) char Ab[TM * 128];
  __shared__ __align__(16) char Bb[TN * 128];
  __shared__ float rowmin2[2][TM];
  __shared__ float sqrow[TM];
  __shared__ float colsq[TN];

  const int t = threadIdx.x;
  const int w = t >> 6;
  const int l = t & 63;
  const int wr = w >> 1, wc = w & 1;
  const int g = l >> 4, lr = l & 15;
  const long row0 = (long)blockIdx.x * TM;

  float runmin[4][4];
#pragma unroll
  for (int m = 0; m < 4; ++m)
#pragma unroll
    for (int r = 0; r < 4; ++r) runmin[m][r] = 3.0e38f;

  float sqpart[8];
#pragma unroll
  for (int c = 0; c < 8; ++c) sqpart[c] = 0.f;

  for (int nt = 0; nt < NT_TILES; ++nt) {
    const int col0 = nt * TN;
    f32x4 acc[4][4];
#pragma unroll
    for (int m = 0; m < 4; ++m)
#pragma unroll
      for (int n = 0; n < 4; ++n) acc[m][n] = (f32x4){0.f, 0.f, 0.f, 0.f};

    float cpart[8];
    if constexpr (!WS) {
#pragma unroll
      for (int c = 0; c < 8; ++c) cpart[c] = 0.f;
    }

    for (int kt = 0; kt < KT_STEPS; ++kt) {
      __syncthreads();
      if constexpr (WS) {
#pragma unroll
        for (int i = 0; i < 4; ++i) {
          const int s = (w * 4 + i) * 64 + l;
          const int col = s >> 3, sl = s & 7;
          const __bf16* src =
              cbf + (size_t)(col0 + col) * D_K + kt * BK + ((sl ^ (col & 7)) << 3);
          __builtin_amdgcn_global_load_lds(
              (const AS1 unsigned int*)(const void*)src,
              (AS3 unsigned int*)(void*)(Bb + (w * 4 + i) * 1024), 16, 0, 0);
        }
      } else {
#pragma unroll
        for (int c = 0; c < 8; ++c) {
          const int f = c * 256 + t;
          const int col = f >> 4, kq = f & 15;
          const float4 v = *reinterpret_cast<const float4*>(
              centf + (size_t)(col0 + col) * D_K + kt * BK + kq * 4);
          cpart[c] += v.x * v.x + v.y * v.y + v.z * v.z + v.w * v.w;
          bf16x4 o = {(__bf16)v.x, (__bf16)v.y, (__bf16)v.z, (__bf16)v.w};
          const int slot = kq >> 1;
          *reinterpret_cast<bf16x4*>(Bb + col * 128 + ((slot ^ (col & 7)) << 4) +
                                     (kq & 1) * 8) = o;
        }
      }
#pragma unroll
      for (int c = 0; c < 8; ++c) {
        const int f = c * 256 + t;
        const int row = f >> 4, kq = f & 15;
        const float4 v = *reinterpret_cast<const float4*>(
            embeds + (row0 + row) * (long)D_K + kt * BK + kq * 4);
        if (nt == 0) sqpart[c] += v.x * v.x + v.y * v.y + v.z * v.z + v.w * v.w;
        bf16x4 o = {(__bf16)v.x, (__bf16)v.y, (__bf16)v.z, (__bf16)v.w};
        const int slot = kq >> 1;
        *reinterpret_cast<bf16x4*>(Ab + row * 128 + ((slot ^ (row & 7)) << 4) +
                                   (kq & 1) * 8) = o;
      }
      __syncthreads();
#pragma unroll
      for (int ks = 0; ks < 2; ++ks) {
        bf16x8 af[4], bfr[4];
#pragma unroll
        for (int m = 0; m < 4; ++m) {
          const int row = wr * 64 + m * 16 + lr;
          const int slot = ks * 4 + g;
          af[m] = *reinterpret_cast<const bf16x8*>(Ab + row * 128 +
                                                   ((slot ^ (row & 7)) << 4));
        }
#pragma unroll
        for (int n = 0; n < 4; ++n) {
          const int col = wc * 64 + n * 16 + lr;
          const int slot = ks * 4 + g;
          bfr[n] = *reinterpret_cast<const bf16x8*>(Bb + col * 128 +
                                                    ((slot ^ (col & 7)) << 4));
        }
#pragma unroll
        for (int m = 0; m < 4; ++m)
#pragma unroll
          for (int n = 0; n < 4; ++n)
            acc[m][n] =
                __builtin_amdgcn_mfma_f32_16x16x32_bf16(af[m], bfr[n], acc[m][n], 0, 0, 0);
      }
    }

    if (nt == 0) {
#pragma unroll
      for (int c = 0; c < 8; ++c) {
        float ss = sqpart[c];
        ss += __shfl_xor(ss, 1);
        ss += __shfl_xor(ss, 2);
        ss += __shfl_xor(ss, 4);
        ss += __shfl_xor(ss, 8);
        if (lr == 0) sqrow[c * 16 + (w * 4 + g)] = ss;
      }
    }
    if constexpr (!WS) {
#pragma unroll
      for (int c = 0; c < 8; ++c) {
        float ss = cpart[c];
        ss += __shfl_xor(ss, 1);
        ss += __shfl_xor(ss, 2);
        ss += __shfl_xor(ss, 4);
        ss += __shfl_xor(ss, 8);
        if (lr == 0) colsq[c * 16 + (w * 4 + g)] = ss;
      }
      __syncthreads();
    }

#pragma unroll
    for (int n = 0; n < 4; ++n) {
      float cs;
      if constexpr (WS)
        cs = csq[col0 + wc * 64 + n * 16 + lr];
      else
        cs = colsq[wc * 64 + n * 16 + lr];
#pragma unroll
      for (int m = 0; m < 4; ++m)
#pragma unroll
        for (int r = 0; r < 4; ++r)
          runmin[m][r] = fminf(runmin[m][r], cs - 2.0f * acc[m][n][r]);
    }
  }

#pragma unroll
  for (int m = 0; m < 4; ++m)
#pragma unroll
    for (int r = 0; r < 4; ++r) {
      float v = runmin[m][r];
      v = fminf(v, __shfl_xor(v, 1));
      v = fminf(v, __shfl_xor(v, 2));
      v = fminf(v, __shfl_xor(v, 4));
      v = fminf(v, __shfl_xor(v, 8));
      runmin[m][r] = v;
    }
  if (lr == 0) {
#pragma unroll
    for (int m = 0; m < 4; ++m)
#pragma unroll
      for (int r = 0; r < 4; ++r)
        rowmin2[wc][wr * 64 + m * 16 + g * 4 + r] = runmin[m][r];
  }
  __syncthreads();
  if (t < TM) {
    const float v = fminf(rowmin2[0][t], rowmin2[1][t]);
    out[row0 + t] = sqrtf(fmaxf(sqrow[t] + v, 0.f));
  }
}

extern "C" void kernel_launch(void* const* d_in, const int* in_sizes, int n_in,
                              void* d_out, int out_size, void* d_ws, size_t ws_size,
                              hipStream_t stream) {
  const float* embeds = (const float*)d_in[0];
  const float* cent = (const float*)d_in[1];
  float* out = (float*)d_out;

  // fast path needs only c8t (2 MiB) + csq (8 KiB)
  const size_t off_c8t = 0;
  const size_t off_csq = off_c8t + (size_t)M_CENT * D_K;  // 2 MiB
  const size_t need_fast = off_csq + (size_t)M_CENT * 4;  // +8 KiB

  if (ws_size >= need_fast) {
    unsigned char* c8t = (unsigned char*)d_ws + off_c8t;
    float* csq = (float*)((char*)d_ws + off_csq);
    rowsq_fp8packT<<<M_CENT, 256, 0, stream>>>(cent, c8t, csq);
    fused_mx<<<NBLKF, 512, 0, stream>>>(embeds, c8t, csq, out);
  } else {
    fused_min<false><<<N_ROWS / TM, 256, 0, stream>>>(embeds, cent, nullptr, nullptr, out);
  }
}

// Round 17
// 388.492 us; speedup vs baseline: 6.6079x; 6.6079x over previous
//
#include <hip/hip_runtime.h>
#include <hip/hip_bf16.h>

// CentroidsFlowAD: out[row] = sqrt(max(||e||^2 + min_col(||c||^2 - 2 e.c), 0))
// rows = 32*3136 = 100352, cols = 2048 centroids, K = 1024.
//
// R17 = R15 structure (A-dbuf LDS + B-direct-from-L2 c8t, one barrier per
// K-tile) with 512-THREAD blocks: 8 waves (2x4), wave tile 64x32 ->
// acc[4][2]=32 regs -> (512,2) = 4 waves/SIMD (16/CU), 128-reg budget,
// in-loop live ~100, no spill. R11/R14/R15 proved the gemm latency-bound
// at 3 waves/SIMD (three schedule variants identical at ~245us); this is
// the +33% TLP the register file previously forbade.
// R16's fusion is REVERTED: per-block full-c8t touring + embeds streaming
// defeated L2/L3 (FETCH 3.4GB, 2567us). Split pipeline restored.
//   1. rowsq_fp8packT on centroids -> c8t (transposed fragment-major) + csq
//   2. rowsq_fp8pack on embeds -> e8 (row-major seg-128) + esq
//   3. gemm_min_mx (512t): per kt: WAITVM(4) -> B1 -> stageA(kt+1->buf^1)
//      -> compute (8 A ds_reads + B regs -> 8 mfma_scale x2) -> loadB(kt+1)
//   4. final_min: 16-way min + sqrt
// e8 row layout (128B per K-seg): slot s=ksp*4+g holds
// k = {32*(2ksp)+8g..+7 | 32*(2ksp+1)+8g..+7}; A slot swizzle s^(row&7).
// c8t: byte ((seg*8+s)*2048 + col)*16 + b -> B-frag loads lane-coalesced.
// Fallback: round-1 fused kernel (proven, bf16).

typedef __bf16 bf16x8 __attribute__((ext_vector_type(8)));
typedef __bf16 bf16x4 __attribute__((ext_vector_type(4)));
typedef float f32x4 __attribute__((ext_vector_type(4)));
typedef int i32x4 __attribute__((ext_vector_type(4)));
typedef int i32x8 __attribute__((ext_vector_type(8)));

#define N_ROWS 100352
#define M_CENT 2048
#define D_K 1024

// fp8 fast-path geometry
#define BM4 128
#define BN4 128
#define BK4 128
#define NT4 (D_K / BK4)                // 8 K-tiles
#define NCT4 (M_CENT / BN4)            // 16 col tiles
#define NBLK4 ((N_ROWS / BM4) * NCT4)  // 12544
#define BPX4 (NBLK4 / 8)               // 1568 per XCD
#define ABUF 16384                     // one A buffer

// fallback geometry (round-1, unchanged)
#define TM 128
#define TN 128
#define BK 64
#define NT_TILES (M_CENT / TN)  // 16
#define KT_STEPS (D_K / BK)     // 16

#define AS1 __attribute__((address_space(1)))
#define AS3 __attribute__((address_space(3)))

#define WAITVM(N) asm volatile("s_waitcnt vmcnt(" #N ")" ::: "memory")
#define FENCE asm volatile("" ::: "memory")

// ---- prep (embeds): fp32 [rows][1024] -> packed fp8 row + row sqnorm ----
// Byte pos in row: seg*128 + (ksp*4+g)*16 + h*8 + j, k = 32*(2ksp+h)+8g+j.
__global__ __launch_bounds__(256) void rowsq_fp8pack(const float* __restrict__ src,
                                                     unsigned char* __restrict__ dst,
                                                     float* __restrict__ sq) {
  const int m = blockIdx.x;   // row
  const int t = threadIdx.x;  // 256 threads * 4 floats = 1024
  const float4 v = *reinterpret_cast<const float4*>(src + (size_t)m * D_K + t * 4);
  int pk = __builtin_amdgcn_cvt_pk_fp8_f32(v.x, v.y, 0, false);
  pk = __builtin_amdgcn_cvt_pk_fp8_f32(v.z, v.w, pk, true);
  const int k = t * 4;
  const int seg = k >> 7;
  const int ksi = (k >> 5) & 3;
  const int g = (k >> 3) & 3;
  const int j = k & 7;  // 0 or 4
  const int p = seg * 128 + (((ksi >> 1) * 4 + g) << 4) + (ksi & 1) * 8 + j;
  *reinterpret_cast<unsigned int*>(dst + (size_t)m * D_K + p) = (unsigned int)pk;
  float ss = v.x * v.x + v.y * v.y + v.z * v.z + v.w * v.w;
  ss += __shfl_xor(ss, 1);
  ss += __shfl_xor(ss, 2);
  ss += __shfl_xor(ss, 4);
  ss += __shfl_xor(ss, 8);
  ss += __shfl_xor(ss, 16);
  ss += __shfl_xor(ss, 32);
  __shared__ float ws4[4];
  const int w = t >> 6, l = t & 63;
  if (l == 0) ws4[w] = ss;
  __syncthreads();
  if (t == 0) sq[m] = ws4[0] + ws4[1] + ws4[2] + ws4[3];
}

// ---- prep (centroids): fp32 -> TRANSPOSED fragment-major fp8 + sqnorm ----
// dst byte = ((seg*8 + s)*2048 + m)*16 + h*8 + j, s = ksp*4+g. (verified)
__global__ __launch_bounds__(256) void rowsq_fp8packT(const float* __restrict__ src,
                                                      unsigned char* __restrict__ dst,
                                                      float* __restrict__ sq) {
  const int m = blockIdx.x;   // centroid (becomes column)
  const int t = threadIdx.x;
  const float4 v = *reinterpret_cast<const float4*>(src + (size_t)m * D_K + t * 4);
  int pk = __builtin_amdgcn_cvt_pk_fp8_f32(v.x, v.y, 0, false);
  pk = __builtin_amdgcn_cvt_pk_fp8_f32(v.z, v.w, pk, true);
  const int k = t * 4;
  const int seg = k >> 7;
  const int ksi = (k >> 5) & 3;
  const int g = (k >> 3) & 3;
  const int j = k & 7;  // 0 or 4
  const int s = (ksi >> 1) * 4 + g;
  const size_t p = ((size_t)(seg * 8 + s) * 2048 + m) * 16 + (ksi & 1) * 8 + j;
  *reinterpret_cast<unsigned int*>(dst + p) = (unsigned int)pk;
  float ss = v.x * v.x + v.y * v.y + v.z * v.z + v.w * v.w;
  ss += __shfl_xor(ss, 1);
  ss += __shfl_xor(ss, 2);
  ss += __shfl_xor(ss, 4);
  ss += __shfl_xor(ss, 8);
  ss += __shfl_xor(ss, 16);
  ss += __shfl_xor(ss, 32);
  __shared__ float ws4[4];
  const int w = t >> 6, l = t & 63;
  if (l == 0) ws4[w] = ss;
  __syncthreads();
  if (t == 0) sq[m] = ws4[0] + ws4[1] + ws4[2] + ws4[3];
}

// ---- fast path: MX fp8, 512 threads, A-dbuf / B-from-L2, 1 bar/tile ----
// 8 waves in 2x4: wr = w>>2 (row half), wc = w&3 (32-col strip).
// LDS: 2 x A[128][128B] = 32 KB + rowmin4 2 KB. 2 blocks/CU, 4 waves/SIMD.
// K-tile kt (buf = kt&1):
//   WAITVM(4) -- retires stageA(kt) (2 oldest); B(kt) auto-vmcnt'd
//   B1        -- all waves' A(kt) landed; buf^1 readers (kt-1) done
//   stageA(kt+1 -> buf^1)   [kt<7]
//   compute: 8 ds_read_b128 (A) + B regs -> 8 mfma_scale (4m x 2n)
//   loadB(kt+1)             [kt<7]  (4 coalesced loads)
__global__ __launch_bounds__(512, 2) void gemm_min_mx(const unsigned char* __restrict__ e8,
                                                      const unsigned char* __restrict__ c8t,
                                                      const float* __restrict__ csq,
                                                      float* __restrict__ pmin) {
  __shared__ __align__(16) char lds[2 * ABUF];
  __shared__ float rowmin4[4][BM4];

  const int t = threadIdx.x;
  const int w = t >> 6;
  const int l = t & 63;
  const int wr = w >> 2, wc = w & 3;  // 2x4 wave grid, 64x32 tiles
  const int g = l >> 4, lr = l & 15;

  // XCD swizzle: XCD k owns swz in [1568k,1568k+1568) = rp in [98k,98k+98)
  // x all 16 ct. c8t (2 MB) L2-resident; A panel (128 KB) reused 16x L2-hot.
  const int b = blockIdx.x;
  const int swz = (b & 7) * BPX4 + (b >> 3);
  const int rp = swz >> 4, ct = swz & 15;
  const long row0 = (long)rp * BM4;
  const int col0 = ct * BN4;

  // A staging (512 threads): load i covers rows i*64 + (t>>3); slot = t&7
  // (row&7 i-invariant). source = row*1024 + kt*128 + ((slot^(row&7))<<4).
  const int trow = t >> 3, tsl = t & 7;
  const int ssw = (tsl ^ (trow & 7)) << 4;
  const unsigned char* srcA0 = e8 + (row0 + trow) * (size_t)D_K + ssw;
  const int dst0 = t * 16;

  // B direct pointers into c8t: frag (n, ksp) at
  //   ((kt*8 + ksp*4 + g)*2048 + col)*16, col = col0 + wc*32 + n*16 + lr.
  const unsigned char* colp[2];
#pragma unroll
  for (int n = 0; n < 2; ++n)
    colp[n] = c8t + ((size_t)g * 2048 + (col0 + wc * 32 + n * 16 + lr)) * 16;

  f32x4 acc[4][2];
#pragma unroll
  for (int m = 0; m < 4; ++m) {
    acc[m][0] = (f32x4){0.f, 0.f, 0.f, 0.f};
    acc[m][1] = (f32x4){0.f, 0.f, 0.f, 0.f};
  }

  // A frag bases: row = wr*64 + m*16 + lr; row&7 == lr&7 -> m-invariant.
  const int swsel = lr & 7;
  const char* aBase0 = lds + (wr * 64 + lr) * 128 + ((g ^ swsel) << 4);
  const char* aBase1 = lds + (wr * 64 + lr) * 128 + (((4 + g) ^ swsel) << 4);

  i32x4 bLo[2], bHi[2];

  auto stageA = [&](int kt, int buf) {
    const size_t ko = (size_t)kt * BK4;
    char* base = lds + buf * ABUF;
#pragma unroll
    for (int i = 0; i < 2; ++i)
      __builtin_amdgcn_global_load_lds(
          (const AS1 unsigned int*)(const void*)(srcA0 + (size_t)i * 64 * D_K + ko),
          (AS3 unsigned int*)(void*)(base + i * 8192 + dst0), 16, 0, 0);
  };

  auto loadB = [&](int kt) {
#pragma unroll
    for (int n = 0; n < 2; ++n) {
      bLo[n] = *reinterpret_cast<const i32x4*>(colp[n] + (size_t)kt * 262144);
      bHi[n] = *reinterpret_cast<const i32x4*>(colp[n] + (size_t)kt * 262144 + 131072);
    }
  };

  // A from LDS + preloaded B -> 8 mfma_scale (K=128, unit e8m0 scales)
  auto compute_tile = [&](int bo) {
    i32x8 b8[2];
#pragma unroll
    for (int n = 0; n < 2; ++n)
      b8[n] = __builtin_shufflevector(bLo[n], bHi[n], 0, 1, 2, 3, 4, 5, 6, 7);
#pragma unroll
    for (int m = 0; m < 4; ++m) {
      const i32x4 lo = *reinterpret_cast<const i32x4*>(aBase0 + bo + m * 2048);
      const i32x4 hi = *reinterpret_cast<const i32x4*>(aBase1 + bo + m * 2048);
      const i32x8 a8 = __builtin_shufflevector(lo, hi, 0, 1, 2, 3, 4, 5, 6, 7);
      acc[m][0] = __builtin_amdgcn_mfma_scale_f32_16x16x128_f8f6f4(
          a8, b8[0], acc[m][0], 0, 0, 0, 0x7F7F7F7F, 0, 0x7F7F7F7F);
      acc[m][1] = __builtin_amdgcn_mfma_scale_f32_16x16x128_f8f6f4(
          a8, b8[1], acc[m][1], 0, 0, 0, 0x7F7F7F7F, 0, 0x7F7F7F7F);
    }
  };

  // prologue: A(0) staged (oldest in queue), then B(0)
  stageA(0, 0);
  FENCE;
  loadB(0);
#pragma unroll
  for (int kt = 0; kt < NT4; ++kt) {
    const int buf = kt & 1;
    WAITVM(4);  // retire 2 oldest = stageA(kt); B(kt) handled by compiler
    FENCE;
    __builtin_amdgcn_s_barrier();  // B1: A(kt) landed; buf^1 reads all done
    FENCE;
    if (kt < NT4 - 1) {
      stageA(kt + 1, buf ^ 1);  // safe: after B1, all reads of buf^1 done
      FENCE;                    // pin issue order: A-stage before B loads
    }
    compute_tile(buf * ABUF);
    if (kt < NT4 - 1) {
      FENCE;
      loadB(kt + 1);  // reuse B regs after last use in compute_tile
    }
  }

  // --- partial min over this block's 128 cols: val = ||c||^2 - 2*dot ---
  float runmin[4][4];
#pragma unroll
  for (int m = 0; m < 4; ++m)
#pragma unroll
    for (int r = 0; r < 4; ++r) runmin[m][r] = 3.0e38f;
#pragma unroll
  for (int n = 0; n < 2; ++n) {
    const float cs = csq[col0 + wc * 32 + n * 16 + lr];
#pragma unroll
    for (int m = 0; m < 4; ++m)
#pragma unroll
      for (int r = 0; r < 4; ++r)
        runmin[m][r] = fminf(runmin[m][r], cs - 2.0f * acc[m][n][r]);
  }
#pragma unroll
  for (int m = 0; m < 4; ++m)
#pragma unroll
    for (int r = 0; r < 4; ++r) {
      float v = runmin[m][r];
      v = fminf(v, __shfl_xor(v, 1));
      v = fminf(v, __shfl_xor(v, 2));
      v = fminf(v, __shfl_xor(v, 4));
      v = fminf(v, __shfl_xor(v, 8));
      runmin[m][r] = v;
    }
  __syncthreads();  // LDS A reads done everywhere before rowmin4 alias use
  if (lr == 0) {
#pragma unroll
    for (int m = 0; m < 4; ++m)
#pragma unroll
      for (int r = 0; r < 4; ++r)
        rowmin4[wc][wr * 64 + m * 16 + g * 4 + r] = runmin[m][r];
  }
  __syncthreads();
  if (t < BM4) {
    const float v = fminf(fminf(rowmin4[0][t], rowmin4[1][t]),
                          fminf(rowmin4[2][t], rowmin4[3][t]));
    pmin[(row0 + t) * NCT4 + ct] = v;
  }
}

// ---- final: 16-way min + sqrt ----
__global__ __launch_bounds__(256) void final_min(const float* __restrict__ esq,
                                                 const float* __restrict__ pmin,
                                                 float* __restrict__ out) {
  const int r = blockIdx.x * 256 + threadIdx.x;
  const float4* p = reinterpret_cast<const float4*>(pmin + (size_t)r * 16);
  float4 a = p[0], b = p[1], c = p[2], d = p[3];
  float m = fminf(fminf(fminf(a.x, a.y), fminf(a.z, a.w)),
                  fminf(fminf(b.x, b.y), fminf(b.z, b.w)));
  m = fminf(m, fminf(fminf(fminf(c.x, c.y), fminf(c.z, c.w)),
                     fminf(fminf(d.x, d.y), fminf(d.z, d.w))));
  out[r] = sqrtf(fmaxf(esq[r] + m, 0.f));
}

// ---- bf16 prep (fallback path) ----
__global__ __launch_bounds__(256) void rowsq_bf16(const float* __restrict__ src,
                                                  __bf16* __restrict__ dst,
                                                  float* __restrict__ sq) {
  const int m = blockIdx.x;
  const int t = threadIdx.x;
  const float4 v = *reinterpret_cast<const float4*>(src + (size_t)m * D_K + t * 4);
  bf16x4 o = {(__bf16)v.x, (__bf16)v.y, (__bf16)v.z, (__bf16)v.w};
  *reinterpret_cast<bf16x4*>(dst + (size_t)m * D_K + t * 4) = o;
  float ss = v.x * v.x + v.y * v.y + v.z * v.z + v.w * v.w;
  ss += __shfl_xor(ss, 1);
  ss += __shfl_xor(ss, 2);
  ss += __shfl_xor(ss, 4);
  ss += __shfl_xor(ss, 8);
  ss += __shfl_xor(ss, 16);
  ss += __shfl_xor(ss, 32);
  __shared__ float ws4[4];
  const int w = t >> 6, l = t & 63;
  if (l == 0) ws4[w] = ss;
  __syncthreads();
  if (t == 0) sq[m] = ws4[0] + ws4[1] + ws4[2] + ws4[3];
}

// =================== round-1 fallback (proven) ===================
template <bool WS>
__global__ __launch_bounds__(256, 2) void fused_min(const float* __restrict__ embeds,
                                                    const float* __restrict__ centf,
                                                    const __bf16* __restrict__ cbf,
                                                    const float* __restrict__ csq,
                                                    float* __restrict__ out) {
  __shared__ __align__(16) char Ab[TM * 128];
  __shared__ __align__(16) char Bb[TN * 128];
  __shared__ float rowmin2[2][TM];
  __shared__ float sqrow[TM];
  __shared__ float colsq[TN];

  const int t = threadIdx.x;
  const int w = t >> 6;
  const int l = t & 63;
  const int wr = w >> 1, wc = w & 1;
  const int g = l >> 4, lr = l & 15;
  const long row0 = (long)blockIdx.x * TM;

  float runmin[4][4];
#pragma unroll
  for (int m = 0; m < 4; ++m)
#pragma unroll
    for (int r = 0; r < 4; ++r) runmin[m][r] = 3.0e38f;

  float sqpart[8];
#pragma unroll
  for (int c = 0; c < 8; ++c) sqpart[c] = 0.f;

  for (int nt = 0; nt < NT_TILES; ++nt) {
    const int col0 = nt * TN;
    f32x4 acc[4][4];
#pragma unroll
    for (int m = 0; m < 4; ++m)
#pragma unroll
      for (int n = 0; n < 4; ++n) acc[m][n] = (f32x4){0.f, 0.f, 0.f, 0.f};

    float cpart[8];
    if constexpr (!WS) {
#pragma unroll
      for (int c = 0; c < 8; ++c) cpart[c] = 0.f;
    }

    for (int kt = 0; kt < KT_STEPS; ++kt) {
      __syncthreads();
      if constexpr (WS) {
#pragma unroll
        for (int i = 0; i < 4; ++i) {
          const int s = (w * 4 + i) * 64 + l;
          const int col = s >> 3, sl = s & 7;
          const __bf16* src =
              cbf + (size_t)(col0 + col) * D_K + kt * BK + ((sl ^ (col & 7)) << 3);
          __builtin_amdgcn_global_load_lds(
              (const AS1 unsigned int*)(const void*)src,
              (AS3 unsigned int*)(void*)(Bb + (w * 4 + i) * 1024), 16, 0, 0);
        }
      } else {
#pragma unroll
        for (int c = 0; c < 8; ++c) {
          const int f = c * 256 + t;
          const int col = f >> 4, kq = f & 15;
          const float4 v = *reinterpret_cast<const float4*>(
              centf + (size_t)(col0 + col) * D_K + kt * BK + kq * 4);
          cpart[c] += v.x * v.x + v.y * v.y + v.z * v.z + v.w * v.w;
          bf16x4 o = {(__bf16)v.x, (__bf16)v.y, (__bf16)v.z, (__bf16)v.w};
          const int slot = kq >> 1;
          *reinterpret_cast<bf16x4*>(Bb + col * 128 + ((slot ^ (col & 7)) << 4) +
                                     (kq & 1) * 8) = o;
        }
      }
#pragma unroll
      for (int c = 0; c < 8; ++c) {
        const int f = c * 256 + t;
        const int row = f >> 4, kq = f & 15;
        const float4 v = *reinterpret_cast<const float4*>(
            embeds + (row0 + row) * (long)D_K + kt * BK + kq * 4);
        if (nt == 0) sqpart[c] += v.x * v.x + v.y * v.y + v.z * v.z + v.w * v.w;
        bf16x4 o = {(__bf16)v.x, (__bf16)v.y, (__bf16)v.z, (__bf16)v.w};
        const int slot = kq >> 1;
        *reinterpret_cast<bf16x4*>(Ab + row * 128 + ((slot ^ (row & 7)) << 4) +
                                   (kq & 1) * 8) = o;
      }
      __syncthreads();
#pragma unroll
      for (int ks = 0; ks < 2; ++ks) {
        bf16x8 af[4], bfr[4];
#pragma unroll
        for (int m = 0; m < 4; ++m) {
          const int row = wr * 64 + m * 16 + lr;
          const int slot = ks * 4 + g;
          af[m] = *reinterpret_cast<const bf16x8*>(Ab + row * 128 +
                                                   ((slot ^ (row & 7)) << 4));
        }
#pragma unroll
        for (int n = 0; n < 4; ++n) {
          const int col = wc * 64 + n * 16 + lr;
          const int slot = ks * 4 + g;
          bfr[n] = *reinterpret_cast<const bf16x8*>(Bb + col * 128 +
                                                    ((slot ^ (col & 7)) << 4));
        }
#pragma unroll
        for (int m = 0; m < 4; ++m)
#pragma unroll
          for (int n = 0; n < 4; ++n)
            acc[m][n] =
                __builtin_amdgcn_mfma_f32_16x16x32_bf16(af[m], bfr[n], acc[m][n], 0, 0, 0);
      }
    }

    if (nt == 0) {
#pragma unroll
      for (int c = 0; c < 8; ++c) {
        float ss = sqpart[c];
        ss += __shfl_xor(ss, 1);
        ss += __shfl_xor(ss, 2);
        ss += __shfl_xor(ss, 4);
        ss += __shfl_xor(ss, 8);
        if (lr == 0) sqrow[c * 16 + (w * 4 + g)] = ss;
      }
    }
    if constexpr (!WS) {
#pragma unroll
      for (int c = 0; c < 8; ++c) {
        float ss = cpart[c];
        ss += __shfl_xor(ss, 1);
        ss += __shfl_xor(ss, 2);
        ss += __shfl_xor(ss, 4);
        ss += __shfl_xor(ss, 8);
        if (lr == 0) colsq[c * 16 + (w * 4 + g)] = ss;
      }
      __syncthreads();
    }

#pragma unroll
    for (int n = 0; n < 4; ++n) {
      float cs;
      if constexpr (WS)
        cs = csq[col0 + wc * 64 + n * 16 + lr];
      else
        cs = colsq[wc * 64 + n * 16 + lr];
#pragma unroll
      for (int m = 0; m < 4; ++m)
#pragma unroll
        for (int r = 0; r < 4; ++r)
          runmin[m][r] = fminf(runmin[m][r], cs - 2.0f * acc[m][n][r]);
    }
  }

#pragma unroll
  for (int m = 0; m < 4; ++m)
#pragma unroll
    for (int r = 0; r < 4; ++r) {
      float v = runmin[m][r];
      v = fminf(v, __shfl_xor(v, 1));
      v = fminf(v, __shfl_xor(v, 2));
      v = fminf(v, __shfl_xor(v, 4));
      v = fminf(v, __shfl_xor(v, 8));
      runmin[m][r] = v;
    }
  if (lr == 0) {
#pragma unroll
    for (int m = 0; m < 4; ++m)
#pragma unroll
      for (int r = 0; r < 4; ++r)
        rowmin2[wc][wr * 64 + m * 16 + g * 4 + r] = runmin[m][r];
  }
  __syncthreads();
  if (t < TM) {
    const float v = fminf(rowmin2[0][t], rowmin2[1][t]);
    out[row0 + t] = sqrtf(fmaxf(sqrow[t] + v, 0.f));
  }
}

extern "C" void kernel_launch(void* const* d_in, const int* in_sizes, int n_in,
                              void* d_out, int out_size, void* d_ws, size_t ws_size,
                              hipStream_t stream) {
  const float* embeds = (const float*)d_in[0];
  const float* cent = (const float*)d_in[1];
  float* out = (float*)d_out;

  // ws layout for the fp8 fast path (~112 MiB)
  const size_t off_c8 = 0;
  const size_t off_csq = off_c8 + (size_t)M_CENT * D_K;             // 2 MiB
  const size_t off_e8 = off_csq + (size_t)M_CENT * 4;               // +8 KiB
  const size_t off_esq = off_e8 + (size_t)N_ROWS * D_K;             // +98 MiB
  const size_t off_pmin = off_esq + (size_t)N_ROWS * 4;             // +392 KiB
  const size_t need_full = off_pmin + (size_t)N_ROWS * NCT4 * 4;    // +6.1 MiB
  const size_t need_small = (size_t)M_CENT * D_K * 2 + (size_t)M_CENT * 4;

  if (ws_size >= need_full) {
    unsigned char* c8t = (unsigned char*)d_ws + off_c8;
    float* csq = (float*)((char*)d_ws + off_csq);
    unsigned char* e8 = (unsigned char*)d_ws + off_e8;
    float* esq = (float*)((char*)d_ws + off_esq);
    float* pmin = (float*)((char*)d_ws + off_pmin);
    rowsq_fp8packT<<<M_CENT, 256, 0, stream>>>(cent, c8t, csq);
    rowsq_fp8pack<<<N_ROWS, 256, 0, stream>>>(embeds, e8, esq);
    gemm_min_mx<<<NBLK4, 512, 0, stream>>>(e8, c8t, csq, pmin);
    final_min<<<N_ROWS / 256, 256, 0, stream>>>(esq, pmin, out);
  } else if (ws_size >= need_small) {
    __bf16* cbf = (__bf16*)d_ws;
    float* csq = (float*)((char*)d_ws + (size_t)M_CENT * D_K * 2);
    rowsq_bf16<<<M_CENT, 256, 0, stream>>>(cent, cbf, csq);
    fused_min<true><<<N_ROWS / TM, 256, 0, stream>>>(embeds, cent, cbf, csq, out);
  } else {
    fused_min<false><<<N_ROWS / TM, 256, 0, stream>>>(embeds, cent, nullptr, nullptr, out);
  }
}

// Round 18
// 332.898 us; speedup vs baseline: 7.7114x; 1.1670x over previous
//
#include <hip/hip_runtime.h>
#include <hip/hip_bf16.h>

// CentroidsFlowAD: out[row] = sqrt(max(||e||^2 + min_col(||c||^2 - 2 e.c), 0))
// rows = 32*3136 = 100352, cols = 2048 centroids, K = 1024.
//
// R18 = R11's verified kernel (single 32KB buffer, 2-barrier schedule,
// MX 16x16x128, 128x128 tile, 64x64 wave tile) at 4 BLOCKS/CU.
// Occupancy matrix so far: 64x64 waves @3blk = 250us (R11/R14/R15,
// latency-bound, no pipe >40%); 64x32 waves @~5blk = 314us (R17: half the
// MFMA per wave's fixed latency chain); MX @4blk previously SPILLED
// (R9/R10: all 4 B-frags live + shuffle copies > 64 arch regs).
// R18's fix: TWO-HALF B pass -- load b8[0..1], m-loop for n=0,1, then
// b8[2..3] for n=2,3, reloading a8 per half. B-live 32->16 regs; A
// ds_reads double (LDS proven non-binding, R14). Arch live ~60 <= 64
// -> fits (256,4)'s 128-reg unified budget with acc=64.
// R8 proved 4-block TLP at this wave tile reaches 70% MfmaUtil.
// WRITE_SIZE is the spill sentinel (~6 MB clean; 100s MB = spill).
//   1. rowsq_fp8pack centroids -> c8 + csq ; embeds -> e8 + esq
//   2. gemm_min_mx (256t, 4blk): per kt: WAITVM(0) -> B1 -> compute
//      (2 B-halves) -> LGKM0 -> B2 -> stage(kt+1)
//   3. final_min: 16-way min + sqrt
// fp8 K-packed row layout (128B per K-seg): slot s=ksp*4+g holds
// k = {32*(2ksp)+8g..+7 | 32*(2ksp+1)+8g..+7}; slot swizzle s^(row&7).
// Fallback: round-1 fused kernel (proven, bf16).

typedef __bf16 bf16x8 __attribute__((ext_vector_type(8)));
typedef __bf16 bf16x4 __attribute__((ext_vector_type(4)));
typedef float f32x4 __attribute__((ext_vector_type(4)));
typedef int i32x4 __attribute__((ext_vector_type(4)));
typedef int i32x8 __attribute__((ext_vector_type(8)));

#define N_ROWS 100352
#define M_CENT 2048
#define D_K 1024

// fp8 fast-path geometry
#define BM4 128
#define BN4 128
#define BK4 128
#define NT4 (D_K / BK4)                // 8 K-tiles
#define NCT4 (M_CENT / BN4)            // 16 col tiles
#define NBLK4 ((N_ROWS / BM4) * NCT4)  // 12544
#define BPX4 (NBLK4 / 8)               // 1568 per XCD

// fallback geometry (round-1, unchanged)
#define TM 128
#define TN 128
#define BK 64
#define NT_TILES (M_CENT / TN)  // 16
#define KT_STEPS (D_K / BK)     // 16

#define AS1 __attribute__((address_space(1)))
#define AS3 __attribute__((address_space(3)))

#define WAITVM(N) asm volatile("s_waitcnt vmcnt(" #N ")" ::: "memory")
#define LGKM0 asm volatile("s_waitcnt lgkmcnt(0)" ::: "memory")
#define FENCE asm volatile("" ::: "memory")

// ---- prep: fp32 [rows][1024] -> packed fp8 row + per-row squared norm ----
// Packed byte position within row: seg(=128-K-seg)*128 + (ksp*4+g)*16 + h*8 + j
// where k = 32*(2*ksp+h) + 8*g + j.   (R5 layout, proven R5-R15.)
__global__ __launch_bounds__(256) void rowsq_fp8pack(const float* __restrict__ src,
                                                     unsigned char* __restrict__ dst,
                                                     float* __restrict__ sq) {
  const int m = blockIdx.x;   // row
  const int t = threadIdx.x;  // 256 threads * 4 floats = 1024
  const float4 v = *reinterpret_cast<const float4*>(src + (size_t)m * D_K + t * 4);
  int pk = __builtin_amdgcn_cvt_pk_fp8_f32(v.x, v.y, 0, false);
  pk = __builtin_amdgcn_cvt_pk_fp8_f32(v.z, v.w, pk, true);
  const int k = t * 4;
  const int seg = k >> 7;
  const int ksi = (k >> 5) & 3;
  const int g = (k >> 3) & 3;
  const int j = k & 7;  // 0 or 4
  const int p = seg * 128 + (((ksi >> 1) * 4 + g) << 4) + (ksi & 1) * 8 + j;
  *reinterpret_cast<unsigned int*>(dst + (size_t)m * D_K + p) = (unsigned int)pk;
  float ss = v.x * v.x + v.y * v.y + v.z * v.z + v.w * v.w;
  ss += __shfl_xor(ss, 1);
  ss += __shfl_xor(ss, 2);
  ss += __shfl_xor(ss, 4);
  ss += __shfl_xor(ss, 8);
  ss += __shfl_xor(ss, 16);
  ss += __shfl_xor(ss, 32);
  __shared__ float ws4[4];
  const int w = t >> 6, l = t & 63;
  if (l == 0) ws4[w] = ss;
  __syncthreads();
  if (t == 0) sq[m] = ws4[0] + ws4[1] + ws4[2] + ws4[3];
}

// ---- fast path: MX fp8, 128x128 tile, BK=128, single buf, 4 blk/CU ----
// LDS: A[128][128B] 16K | B[128][128B] 16K = 32 KB (+1 KB rowmin).
// K-tile kt:
//   WAITVM(0) -> B1 (read-safety, all waves' stage landed)
//   compute: two B-halves {load b8[2], m-loop (a8 reload)} -- B-live 16 regs
//   LGKM0 -> B2 (WAR-safety) -> stage(kt+1)
// No setprio (R7). 4-block phase-mixed TLP hides the drain (R8).
__global__ __launch_bounds__(256, 4) void gemm_min_mx(const unsigned char* __restrict__ e8,
                                                      const unsigned char* __restrict__ c8,
                                                      const float* __restrict__ csq,
                                                      float* __restrict__ pmin) {
  __shared__ __align__(16) char lds[32768];
  __shared__ float rowmin2[2][BM4];

  const int t = threadIdx.x;
  const int w = t >> 6;
  const int l = t & 63;
  const int wr = w >> 1, wc = w & 1;  // 2x2 wave grid, 64x64 tiles
  const int g = l >> 4, lr = l & 15;

  // XCD swizzle: XCD k owns swz in [1568k,1568k+1568) = rp in [98k,98k+98)
  // x all 16 ct. c8 (2 MB) L2-resident; A panel (128 KB) reused 16x L2-hot.
  const int b = blockIdx.x;
  const int swz = (b & 7) * BPX4 + (b >> 3);
  const int rp = swz >> 4, ct = swz & 15;
  const long row0 = (long)rp * BM4;
  const int col0 = ct * BN4;

  // staging: dest linear d = i*4096 + t*16 -> row = i*32 + (t>>3), slot = t&7
  // (row&7 i-invariant). source = row*1024 + kt*128 + ((slot^(row&7))<<4).
  const int trow = t >> 3, tsl = t & 7;
  const int ssw = (tsl ^ (trow & 7)) << 4;
  const unsigned char* srcA0 = e8 + (row0 + trow) * (size_t)D_K + ssw;
  const unsigned char* srcB0 = c8 + (size_t)(col0 + trow) * D_K + ssw;
  const int dst0 = t * 16;

  f32x4 acc[4][4];
#pragma unroll
  for (int m = 0; m < 4; ++m)
#pragma unroll
    for (int n = 0; n < 4; ++n) acc[m][n] = (f32x4){0.f, 0.f, 0.f, 0.f};

  // Lean frag addressing: row&7 == lr&7 independent of m/wr -> m-invariant
  // swizzle. 4 LDS base addrs + imm m*2048/n*2048.
  const int swsel = lr & 7;
  const char* aBase0 = lds + (wr * 64 + lr) * 128 + ((g ^ swsel) << 4);
  const char* aBase1 = lds + (wr * 64 + lr) * 128 + (((4 + g) ^ swsel) << 4);
  const char* bBase0 = lds + 16384 + (wc * 64 + lr) * 128 + ((g ^ swsel) << 4);
  const char* bBase1 = lds + 16384 + (wc * 64 + lr) * 128 + (((4 + g) ^ swsel) << 4);

  auto stage = [&](int kt) {
    const size_t ko = (size_t)kt * BK4;
#pragma unroll
    for (int i = 0; i < 4; ++i)
      __builtin_amdgcn_global_load_lds(
          (const AS1 unsigned int*)(const void*)(srcA0 + (size_t)i * 32 * D_K + ko),
          (AS3 unsigned int*)(void*)(lds + i * 4096 + dst0), 16, 0, 0);
#pragma unroll
    for (int i = 0; i < 4; ++i)
      __builtin_amdgcn_global_load_lds(
          (const AS1 unsigned int*)(const void*)(srcB0 + (size_t)i * 32 * D_K + ko),
          (AS3 unsigned int*)(void*)(lds + 16384 + i * 4096 + dst0), 16, 0, 0);
  };

  // one n-half: load 2 B frags, m-loop with per-m a8 reload (B-live 16 regs)
  auto compute_half = [&](int nh) {
    i32x8 b8[2];
#pragma unroll
    for (int n2 = 0; n2 < 2; ++n2) {
      const int n = nh * 2 + n2;
      const i32x4 lo = *reinterpret_cast<const i32x4*>(bBase0 + n * 2048);
      const i32x4 hi = *reinterpret_cast<const i32x4*>(bBase1 + n * 2048);
      b8[n2] = __builtin_shufflevector(lo, hi, 0, 1, 2, 3, 4, 5, 6, 7);
    }
#pragma unroll
    for (int m = 0; m < 4; ++m) {
      const i32x4 lo = *reinterpret_cast<const i32x4*>(aBase0 + m * 2048);
      const i32x4 hi = *reinterpret_cast<const i32x4*>(aBase1 + m * 2048);
      const i32x8 a8 = __builtin_shufflevector(lo, hi, 0, 1, 2, 3, 4, 5, 6, 7);
      acc[m][nh * 2 + 0] = __builtin_amdgcn_mfma_scale_f32_16x16x128_f8f6f4(
          a8, b8[0], acc[m][nh * 2 + 0], 0, 0, 0, 0x7F7F7F7F, 0, 0x7F7F7F7F);
      acc[m][nh * 2 + 1] = __builtin_amdgcn_mfma_scale_f32_16x16x128_f8f6f4(
          a8, b8[1], acc[m][nh * 2 + 1], 0, 0, 0, 0x7F7F7F7F, 0, 0x7F7F7F7F);
    }
  };

  stage(0);
#pragma unroll
  for (int kt = 0; kt < NT4; ++kt) {
    WAITVM(0);  // my stage(kt) landed (4-block TLP hides the drain)
    FENCE;
    __builtin_amdgcn_s_barrier();  // B1: tile kt fully landed (all waves)
    FENCE;
    compute_half(0);
    compute_half(1);
    if (kt < NT4 - 1) {
      LGKM0;  // all reads consumed by MFMAs already
      FENCE;
      __builtin_amdgcn_s_barrier();  // B2: all waves' reads done
      FENCE;
      stage(kt + 1);  // overwrite; lands before next WAITVM(0)
    }
  }

  // --- partial min over this block's 128 cols: val = ||c||^2 - 2*dot ---
  float runmin[4][4];
#pragma unroll
  for (int m = 0; m < 4; ++m)
#pragma unroll
    for (int r = 0; r < 4; ++r) runmin[m][r] = 3.0e38f;
#pragma unroll
  for (int n = 0; n < 4; ++n) {
    const float cs = csq[col0 + wc * 64 + n * 16 + lr];
#pragma unroll
    for (int m = 0; m < 4; ++m)
#pragma unroll
      for (int r = 0; r < 4; ++r)
        runmin[m][r] = fminf(runmin[m][r], cs - 2.0f * acc[m][n][r]);
  }
#pragma unroll
  for (int m = 0; m < 4; ++m)
#pragma unroll
    for (int r = 0; r < 4; ++r) {
      float v = runmin[m][r];
      v = fminf(v, __shfl_xor(v, 1));
      v = fminf(v, __shfl_xor(v, 2));
      v = fminf(v, __shfl_xor(v, 4));
      v = fminf(v, __shfl_xor(v, 8));
      runmin[m][r] = v;
    }
  if (lr == 0) {
#pragma unroll
    for (int m = 0; m < 4; ++m)
#pragma unroll
      for (int r = 0; r < 4; ++r)
        rowmin2[wc][wr * 64 + m * 16 + g * 4 + r] = runmin[m][r];
  }
  __syncthreads();
  if (t < BM4) {
    pmin[(row0 + t) * NCT4 + ct] = fminf(rowmin2[0][t], rowmin2[1][t]);
  }
}

// ---- final: 16-way min + sqrt ----
__global__ __launch_bounds__(256) void final_min(const float* __restrict__ esq,
                                                 const float* __restrict__ pmin,
                                                 float* __restrict__ out) {
  const int r = blockIdx.x * 256 + threadIdx.x;
  const float4* p = reinterpret_cast<const float4*>(pmin + (size_t)r * 16);
  float4 a = p[0], b = p[1], c = p[2], d = p[3];
  float m = fminf(fminf(fminf(a.x, a.y), fminf(a.z, a.w)),
                  fminf(fminf(b.x, b.y), fminf(b.z, b.w)));
  m = fminf(m, fminf(fminf(fminf(c.x, c.y), fminf(c.z, c.w)),
                     fminf(fminf(d.x, d.y), fminf(d.z, d.w))));
  out[r] = sqrtf(fmaxf(esq[r] + m, 0.f));
}

// ---- bf16 prep (fallback path) ----
__global__ __launch_bounds__(256) void rowsq_bf16(const float* __restrict__ src,
                                                  __bf16* __restrict__ dst,
                                                  float* __restrict__ sq) {
  const int m = blockIdx.x;
  const int t = threadIdx.x;
  const float4 v = *reinterpret_cast<const float4*>(src + (size_t)m * D_K + t * 4);
  bf16x4 o = {(__bf16)v.x, (__bf16)v.y, (__bf16)v.z, (__bf16)v.w};
  *reinterpret_cast<bf16x4*>(dst + (size_t)m * D_K + t * 4) = o;
  float ss = v.x * v.x + v.y * v.y + v.z * v.z + v.w * v.w;
  ss += __shfl_xor(ss, 1);
  ss += __shfl_xor(ss, 2);
  ss += __shfl_xor(ss, 4);
  ss += __shfl_xor(ss, 8);
  ss += __shfl_xor(ss, 16);
  ss += __shfl_xor(ss, 32);
  __shared__ float ws4[4];
  const int w = t >> 6, l = t & 63;
  if (l == 0) ws4[w] = ss;
  __syncthreads();
  if (t == 0) sq[m] = ws4[0] + ws4[1] + ws4[2] + ws4[3];
}

// =================== round-1 fallback (proven) ===================
template <bool WS>
__global__ __launch_bounds__(256, 2) void fused_min(const float* __restrict__ embeds,
                                                    const float* __restrict__ centf,
                                                    const __bf16* __restrict__ cbf,
                                                    const float* __restrict__ csq,
                                                    float* __restrict__ out) {
  __shared__ __align__(16) char Ab[TM * 128];
  __shared__ __align__(16) char Bb[TN * 128];
  __shared__ float rowmin2[2][TM];
  __shared__ float sqrow[TM];
  __shared__ float colsq[TN];

  const int t = threadIdx.x;
  const int w = t >> 6;
  const int l = t & 63;
  const int wr = w >> 1, wc = w & 1;
  const int g = l >> 4, lr = l & 15;
  const long row0 = (long)blockIdx.x * TM;

  float runmin[4][4];
#pragma unroll
  for (int m = 0; m < 4; ++m)
#pragma unroll
    for (int r = 0; r < 4; ++r) runmin[m][r] = 3.0e38f;

  float sqpart[8];
#pragma unroll
  for (int c = 0; c < 8; ++c) sqpart[c] = 0.f;

  for (int nt = 0; nt < NT_TILES; ++nt) {
    const int col0 = nt * TN;
    f32x4 acc[4][4];
#pragma unroll
    for (int m = 0; m < 4; ++m)
#pragma unroll
      for (int n = 0; n < 4; ++n) acc[m][n] = (f32x4){0.f, 0.f, 0.f, 0.f};

    float cpart[8];
    if constexpr (!WS) {
#pragma unroll
      for (int c = 0; c < 8; ++c) cpart[c] = 0.f;
    }

    for (int kt = 0; kt < KT_STEPS; ++kt) {
      __syncthreads();
      if constexpr (WS) {
#pragma unroll
        for (int i = 0; i < 4; ++i) {
          const int s = (w * 4 + i) * 64 + l;
          const int col = s >> 3, sl = s & 7;
          const __bf16* src =
              cbf + (size_t)(col0 + col) * D_K + kt * BK + ((sl ^ (col & 7)) << 3);
          __builtin_amdgcn_global_load_lds(
              (const AS1 unsigned int*)(const void*)src,
              (AS3 unsigned int*)(void*)(Bb + (w * 4 + i) * 1024), 16, 0, 0);
        }
      } else {
#pragma unroll
        for (int c = 0; c < 8; ++c) {
          const int f = c * 256 + t;
          const int col = f >> 4, kq = f & 15;
          const float4 v = *reinterpret_cast<const float4*>(
              centf + (size_t)(col0 + col) * D_K + kt * BK + kq * 4);
          cpart[c] += v.x * v.x + v.y * v.y + v.z * v.z + v.w * v.w;
          bf16x4 o = {(__bf16)v.x, (__bf16)v.y, (__bf16)v.z, (__bf16)v.w};
          const int slot = kq >> 1;
          *reinterpret_cast<bf16x4*>(Bb + col * 128 + ((slot ^ (col & 7)) << 4) +
                                     (kq & 1) * 8) = o;
        }
      }
#pragma unroll
      for (int c = 0; c < 8; ++c) {
        const int f = c * 256 + t;
        const int row = f >> 4, kq = f & 15;
        const float4 v = *reinterpret_cast<const float4*>(
            embeds + (row0 + row) * (long)D_K + kt * BK + kq * 4);
        if (nt == 0) sqpart[c] += v.x * v.x + v.y * v.y + v.z * v.z + v.w * v.w;
        bf16x4 o = {(__bf16)v.x, (__bf16)v.y, (__bf16)v.z, (__bf16)v.w};
        const int slot = kq >> 1;
        *reinterpret_cast<bf16x4*>(Ab + row * 128 + ((slot ^ (row & 7)) << 4) +
                                   (kq & 1) * 8) = o;
      }
      __syncthreads();
#pragma unroll
      for (int ks = 0; ks < 2; ++ks) {
        bf16x8 af[4], bfr[4];
#pragma unroll
        for (int m = 0; m < 4; ++m) {
          const int row = wr * 64 + m * 16 + lr;
          const int slot = ks * 4 + g;
          af[m] = *reinterpret_cast<const bf16x8*>(Ab + row * 128 +
                                                   ((slot ^ (row & 7)) << 4));
        }
#pragma unroll
        for (int n = 0; n < 4; ++n) {
          const int col = wc * 64 + n * 16 + lr;
          const int slot = ks * 4 + g;
          bfr[n] = *reinterpret_cast<const bf16x8*>(Bb + col * 128 +
                                                    ((slot ^ (col & 7)) << 4));
        }
#pragma unroll
        for (int m = 0; m < 4; ++m)
#pragma unroll
          for (int n = 0; n < 4; ++n)
            acc[m][n] =
                __builtin_amdgcn_mfma_f32_16x16x32_bf16(af[m], bfr[n], acc[m][n], 0, 0, 0);
      }
    }

    if (nt == 0) {
#pragma unroll
      for (int c = 0; c < 8; ++c) {
        float ss = sqpart[c];
        ss += __shfl_xor(ss, 1);
        ss += __shfl_xor(ss, 2);
        ss += __shfl_xor(ss, 4);
        ss += __shfl_xor(ss, 8);
        if (lr == 0) sqrow[c * 16 + (w * 4 + g)] = ss;
      }
    }
    if constexpr (!WS) {
#pragma unroll
      for (int c = 0; c < 8; ++c) {
        float ss = cpart[c];
        ss += __shfl_xor(ss, 1);
        ss += __shfl_xor(ss, 2);
        ss += __shfl_xor(ss, 4);
        ss += __shfl_xor(ss, 8);
        if (lr == 0) colsq[c * 16 + (w * 4 + g)] = ss;
      }
      __syncthreads();
    }

#pragma unroll
    for (int n = 0; n < 4; ++n) {
      float cs;
      if constexpr (WS)
        cs = csq[col0 + wc * 64 + n * 16 + lr];
      else
        cs = colsq[wc * 64 + n * 16 + lr];
#pragma unroll
      for (int m = 0; m < 4; ++m)
#pragma unroll
        for (int r = 0; r < 4; ++r)
          runmin[m][r] = fminf(runmin[m][r], cs - 2.0f * acc[m][n][r]);
    }
  }

#pragma unroll
  for (int m = 0; m < 4; ++m)
#pragma unroll
    for (int r = 0; r < 4; ++r) {
      float v = runmin[m][r];
      v = fminf(v, __shfl_xor(v, 1));
      v = fminf(v, __shfl_xor(v, 2));
      v = fminf(v, __shfl_xor(v, 4));
      v = fminf(v, __shfl_xor(v, 8));
      runmin[m][r] = v;
    }
  if (lr == 0) {
#pragma unroll
    for (int m = 0; m < 4; ++m)
#pragma unroll
      for (int r = 0; r < 4; ++r)
        rowmin2[wc][wr * 64 + m * 16 + g * 4 + r] = runmin[m][r];
  }
  __syncthreads();
  if (t < TM) {
    const float v = fminf(rowmin2[0][t], rowmin2[1][t]);
    out[row0 + t] = sqrtf(fmaxf(sqrow[t] + v, 0.f));
  }
}

extern "C" void kernel_launch(void* const* d_in, const int* in_sizes, int n_in,
                              void* d_out, int out_size, void* d_ws, size_t ws_size,
                              hipStream_t stream) {
  const float* embeds = (const float*)d_in[0];
  const float* cent = (const float*)d_in[1];
  float* out = (float*)d_out;

  // ws layout for the fp8 fast path (~112 MiB)
  const size_t off_c8 = 0;
  const size_t off_csq = off_c8 + (size_t)M_CENT * D_K;             // 2 MiB
  const size_t off_e8 = off_csq + (size_t)M_CENT * 4;               // +8 KiB
  const size_t off_esq = off_e8 + (size_t)N_ROWS * D_K;             // +98 MiB
  const size_t off_pmin = off_esq + (size_t)N_ROWS * 4;             // +392 KiB
  const size_t need_full = off_pmin + (size_t)N_ROWS * NCT4 * 4;    // +6.1 MiB
  const size_t need_small = (size_t)M_CENT * D_K * 2 + (size_t)M_CENT * 4;

  if (ws_size >= need_full) {
    unsigned char* c8 = (unsigned char*)d_ws + off_c8;
    float* csq = (float*)((char*)d_ws + off_csq);
    unsigned char* e8 = (unsigned char*)d_ws + off_e8;
    float* esq = (float*)((char*)d_ws + off_esq);
    float* pmin = (float*)((char*)d_ws + off_pmin);
    rowsq_fp8pack<<<M_CENT, 256, 0, stream>>>(cent, c8, csq);
    rowsq_fp8pack<<<N_ROWS, 256, 0, stream>>>(embeds, e8, esq);
    gemm_min_mx<<<NBLK4, 256, 0, stream>>>(e8, c8, csq, pmin);
    final_min<<<N_ROWS / 256, 256, 0, stream>>>(esq, pmin, out);
  } else if (ws_size >= need_small) {
    __bf16* cbf = (__bf16*)d_ws;
    float* csq = (float*)((char*)d_ws + (size_t)M_CENT * D_K * 2);
    rowsq_bf16<<<M_CENT, 256, 0, stream>>>(cent, cbf, csq);
    fused_min<true><<<N_ROWS / TM, 256, 0, stream>>>(embeds, cent, cbf, csq, out);
  } else {
    fused_min<false><<<N_ROWS / TM, 256, 0, stream>>>(embeds, cent, nullptr, nullptr, out);
  }
}

// Round 19
// 320.691 us; speedup vs baseline: 8.0050x; 1.0381x over previous
//
#include <hip/hip_runtime.h>
#include <hip/hip_bf16.h>

// CentroidsFlowAD: out[row] = sqrt(max(||e||^2 + min_col(||c||^2 - 2 e.c), 0))
// rows = 32*3136 = 100352, cols = 2048 centroids, K = 1024.
//
// FINAL (R19 = R11, the session's best: 320.05 us total, no spill).
// Fast path (needs ~112 MiB ws), fp8 e4m3 cross-term (row norms exact fp32):
//   1. rowsq_fp8pack on centroids -> c8 (packed fp8, seg-128 layout) + csq
//   2. rowsq_fp8pack on embeds    -> e8 + esq   (HBM-bound, ~78us floor)
//   3. gemm_min_mx: 128x128 tile, BK=128, 4 waves (64x64), single-buffer
//      LDS 33 KB, MX-scaled mfma_scale 16x16x128 (unit e8m0 scales),
//      launch_bounds(256,3) -> 168-reg unified budget, 3 blocks/CU,
//      no spill. ~250us: the measured plateau across SIX structural
//      variants (1-buf/2-bar, dbuf/1-bar, direct-B, 512t, 4blk-spill) --
//      latency-structure-bound, no pipe >40%; registers forbid more
//      waves at the required >=64x64 wave tile (R17: thinner waves lose).
//   4. final_min: 16-way min + sqrt
// Session ledger: bf16 2-phase 128^2 ~50% wall (R0-R7, setprio removal
// +3.5%) -> 4blk TLP 70% MfmaUtil (R8) -> MX 2.28x FLOP/inst (R9) ->
// unified-regfile spill diagnosis (R10/R11: (256,4)=128 regs total incl.
// acc) -> B-from-L2 & schedule variants all neutral (R13-R15) -> fusion
// defeats L2/L3 (R16) -> geometry matrix closed (R17/R18).
// fp8 K-packed row layout (128B per K-seg of 128): 16B slot s=ksp*4+g holds
// k = {32*(2ksp)+8g..+7 | 32*(2ksp+1)+8g..+7}. Lane (g,lr) reading slots
// g and 4+g gets k-blocks 0..3 in register order = one x128 MFMA operand.
// Slot swizzle s^(row&7) (full 8-spread; verified R5-R18).
// Fallback: round-1 fused kernel (proven, bf16).

typedef __bf16 bf16x8 __attribute__((ext_vector_type(8)));
typedef __bf16 bf16x4 __attribute__((ext_vector_type(4)));
typedef float f32x4 __attribute__((ext_vector_type(4)));
typedef int i32x4 __attribute__((ext_vector_type(4)));
typedef int i32x8 __attribute__((ext_vector_type(8)));

#define N_ROWS 100352
#define M_CENT 2048
#define D_K 1024

// fp8 fast-path geometry
#define BM4 128
#define BN4 128
#define BK4 128
#define NT4 (D_K / BK4)                // 8 K-tiles
#define NCT4 (M_CENT / BN4)            // 16 col tiles
#define NBLK4 ((N_ROWS / BM4) * NCT4)  // 12544
#define BPX4 (NBLK4 / 8)               // 1568 per XCD

// fallback geometry (round-1, unchanged)
#define TM 128
#define TN 128
#define BK 64
#define NT_TILES (M_CENT / TN)  // 16
#define KT_STEPS (D_K / BK)     // 16

#define AS1 __attribute__((address_space(1)))
#define AS3 __attribute__((address_space(3)))

#define WAITVM(N) asm volatile("s_waitcnt vmcnt(" #N ")" ::: "memory")
#define LGKM0 asm volatile("s_waitcnt lgkmcnt(0)" ::: "memory")
#define FENCE asm volatile("" ::: "memory")

// ---- prep: fp32 [rows][1024] -> packed fp8 row + per-row squared norm ----
// Packed byte position within row: seg(=128-K-seg)*128 + (ksp*4+g)*16 + h*8 + j
// where k = 32*(2*ksp+h) + 8*g + j.   (R5 layout, proven R5-R18.)
__global__ __launch_bounds__(256) void rowsq_fp8pack(const float* __restrict__ src,
                                                     unsigned char* __restrict__ dst,
                                                     float* __restrict__ sq) {
  const int m = blockIdx.x;   // row
  const int t = threadIdx.x;  // 256 threads * 4 floats = 1024
  const float4 v = *reinterpret_cast<const float4*>(src + (size_t)m * D_K + t * 4);
  int pk = __builtin_amdgcn_cvt_pk_fp8_f32(v.x, v.y, 0, false);
  pk = __builtin_amdgcn_cvt_pk_fp8_f32(v.z, v.w, pk, true);
  const int k = t * 4;
  const int seg = k >> 7;
  const int ksi = (k >> 5) & 3;
  const int g = (k >> 3) & 3;
  const int j = k & 7;  // 0 or 4
  const int p = seg * 128 + (((ksi >> 1) * 4 + g) << 4) + (ksi & 1) * 8 + j;
  *reinterpret_cast<unsigned int*>(dst + (size_t)m * D_K + p) = (unsigned int)pk;
  float ss = v.x * v.x + v.y * v.y + v.z * v.z + v.w * v.w;
  ss += __shfl_xor(ss, 1);
  ss += __shfl_xor(ss, 2);
  ss += __shfl_xor(ss, 4);
  ss += __shfl_xor(ss, 8);
  ss += __shfl_xor(ss, 16);
  ss += __shfl_xor(ss, 32);
  __shared__ float ws4[4];
  const int w = t >> 6, l = t & 63;
  if (l == 0) ws4[w] = ss;
  __syncthreads();
  if (t == 0) sq[m] = ws4[0] + ws4[1] + ws4[2] + ws4[3];
}

// ---- fast path: MX-scaled fp8, 128x128 tile, BK=128, single buf, 3 blk/CU ----
// LDS: A[128 rows][128 B] 16K | B[128][128 B] 16K = 32 KB (+1 KB rowmin).
// K-tile kt:
//   WAITVM(0) -> B1 (read-safety, all waves' stage landed)
//   16 ds_read_b128 -> 16 x mfma_scale 16x16x128 (compiler-interleaved)
//   LGKM0 -> B2 (WAR-safety) -> stage(kt+1)
// No setprio (R7: -3.5%).
__global__ __launch_bounds__(256, 3) void gemm_min_mx(const unsigned char* __restrict__ e8,
                                                      const unsigned char* __restrict__ c8,
                                                      const float* __restrict__ csq,
                                                      float* __restrict__ pmin) {
  __shared__ __align__(16) char lds[32768];
  __shared__ float rowmin2[2][BM4];

  const int t = threadIdx.x;
  const int w = t >> 6;
  const int l = t & 63;
  const int wr = w >> 1, wc = w & 1;  // 2x2 wave grid, 64x64 tiles
  const int g = l >> 4, lr = l & 15;

  // XCD swizzle: XCD k owns swz in [1568k,1568k+1568) = rp in [98k,98k+98)
  // x all 16 ct. c8 (2 MB) L2-resident; A panel (128 KB) reused 16x L2-hot.
  const int b = blockIdx.x;
  const int swz = (b & 7) * BPX4 + (b >> 3);
  const int rp = swz >> 4, ct = swz & 15;
  const long row0 = (long)rp * BM4;
  const int col0 = ct * BN4;

  // staging: dest linear d = i*4096 + t*16 -> row = i*32 + (t>>3), slot = t&7
  // (row&7 i-invariant). source = row*1024 + kt*128 + ((slot^(row&7))<<4).
  const int trow = t >> 3, tsl = t & 7;
  const int ssw = (tsl ^ (trow & 7)) << 4;
  const unsigned char* srcA0 = e8 + (row0 + trow) * (size_t)D_K + ssw;
  const unsigned char* srcB0 = c8 + (size_t)(col0 + trow) * D_K + ssw;
  const int dst0 = t * 16;

  f32x4 acc[4][4];
#pragma unroll
  for (int m = 0; m < 4; ++m)
#pragma unroll
    for (int n = 0; n < 4; ++n) acc[m][n] = (f32x4){0.f, 0.f, 0.f, 0.f};

  // Lean frag addressing: row&7 == lr&7 independent of m/wr, so the
  // swizzled slot offset is m-invariant. 4 base addrs + imm m*2048/n*2048.
  const int swsel = lr & 7;
  const char* aBase0 = lds + (wr * 64 + lr) * 128 + ((g ^ swsel) << 4);
  const char* aBase1 = lds + (wr * 64 + lr) * 128 + (((4 + g) ^ swsel) << 4);
  const char* bBase0 = lds + 16384 + (wc * 64 + lr) * 128 + ((g ^ swsel) << 4);
  const char* bBase1 = lds + 16384 + (wc * 64 + lr) * 128 + (((4 + g) ^ swsel) << 4);

  auto stage = [&](int kt) {
    const size_t ko = (size_t)kt * BK4;
#pragma unroll
    for (int i = 0; i < 4; ++i)
      __builtin_amdgcn_global_load_lds(
          (const AS1 unsigned int*)(const void*)(srcA0 + (size_t)i * 32 * D_K + ko),
          (AS3 unsigned int*)(void*)(lds + i * 4096 + dst0), 16, 0, 0);
#pragma unroll
    for (int i = 0; i < 4; ++i)
      __builtin_amdgcn_global_load_lds(
          (const AS1 unsigned int*)(const void*)(srcB0 + (size_t)i * 32 * D_K + ko),
          (AS3 unsigned int*)(void*)(lds + 16384 + i * 4096 + dst0), 16, 0, 0);
  };

  // read frags + MFMA for one K-tile (K=128 per MFMA, unit e8m0 scales)
  auto compute_tile = [&]() {
    i32x8 b8[4];
#pragma unroll
    for (int n = 0; n < 4; ++n) {
      const i32x4 lo = *reinterpret_cast<const i32x4*>(bBase0 + n * 2048);
      const i32x4 hi = *reinterpret_cast<const i32x4*>(bBase1 + n * 2048);
      b8[n] = __builtin_shufflevector(lo, hi, 0, 1, 2, 3, 4, 5, 6, 7);
    }
#pragma unroll
    for (int m = 0; m < 4; ++m) {
      const i32x4 lo = *reinterpret_cast<const i32x4*>(aBase0 + m * 2048);
      const i32x4 hi = *reinterpret_cast<const i32x4*>(aBase1 + m * 2048);
      const i32x8 a8 = __builtin_shufflevector(lo, hi, 0, 1, 2, 3, 4, 5, 6, 7);
#pragma unroll
      for (int n = 0; n < 4; ++n)
        acc[m][n] = __builtin_amdgcn_mfma_scale_f32_16x16x128_f8f6f4(
            a8, b8[n], acc[m][n], 0 /*fp8 A*/, 0 /*fp8 B*/, 0, 0x7F7F7F7F, 0,
            0x7F7F7F7F);
    }
  };

  stage(0);
#pragma unroll
  for (int kt = 0; kt < NT4; ++kt) {
    WAITVM(0);  // my stage(kt) landed (cross-block TLP hides the drain)
    FENCE;
    __builtin_amdgcn_s_barrier();  // B1: tile kt fully landed (all waves)
    FENCE;
    compute_tile();
    if (kt < NT4 - 1) {
      LGKM0;  // all reads consumed by MFMAs already
      FENCE;
      __builtin_amdgcn_s_barrier();  // B2: all waves' reads done
      FENCE;
      stage(kt + 1);  // overwrite; lands before next WAITVM(0)
    }
  }

  // --- partial min over this block's 128 cols: val = ||c||^2 - 2*dot ---
  float runmin[4][4];
#pragma unroll
  for (int m = 0; m < 4; ++m)
#pragma unroll
    for (int r = 0; r < 4; ++r) runmin[m][r] = 3.0e38f;
#pragma unroll
  for (int n = 0; n < 4; ++n) {
    const float cs = csq[col0 + wc * 64 + n * 16 + lr];
#pragma unroll
    for (int m = 0; m < 4; ++m)
#pragma unroll
      for (int r = 0; r < 4; ++r)
        runmin[m][r] = fminf(runmin[m][r], cs - 2.0f * acc[m][n][r]);
  }
#pragma unroll
  for (int m = 0; m < 4; ++m)
#pragma unroll
    for (int r = 0; r < 4; ++r) {
      float v = runmin[m][r];
      v = fminf(v, __shfl_xor(v, 1));
      v = fminf(v, __shfl_xor(v, 2));
      v = fminf(v, __shfl_xor(v, 4));
      v = fminf(v, __shfl_xor(v, 8));
      runmin[m][r] = v;
    }
  if (lr == 0) {
#pragma unroll
    for (int m = 0; m < 4; ++m)
#pragma unroll
      for (int r = 0; r < 4; ++r)
        rowmin2[wc][wr * 64 + m * 16 + g * 4 + r] = runmin[m][r];
  }
  __syncthreads();
  if (t < BM4) {
    pmin[(row0 + t) * NCT4 + ct] = fminf(rowmin2[0][t], rowmin2[1][t]);
  }
}

// ---- final: 16-way min + sqrt ----
__global__ __launch_bounds__(256) void final_min(const float* __restrict__ esq,
                                                 const float* __restrict__ pmin,
                                                 float* __restrict__ out) {
  const int r = blockIdx.x * 256 + threadIdx.x;
  const float4* p = reinterpret_cast<const float4*>(pmin + (size_t)r * 16);
  float4 a = p[0], b = p[1], c = p[2], d = p[3];
  float m = fminf(fminf(fminf(a.x, a.y), fminf(a.z, a.w)),
                  fminf(fminf(b.x, b.y), fminf(b.z, b.w)));
  m = fminf(m, fminf(fminf(fminf(c.x, c.y), fminf(c.z, c.w)),
                     fminf(fminf(d.x, d.y), fminf(d.z, d.w))));
  out[r] = sqrtf(fmaxf(esq[r] + m, 0.f));
}

// ---- bf16 prep (fallback path) ----
__global__ __launch_bounds__(256) void rowsq_bf16(const float* __restrict__ src,
                                                  __bf16* __restrict__ dst,
                                                  float* __restrict__ sq) {
  const int m = blockIdx.x;
  const int t = threadIdx.x;
  const float4 v = *reinterpret_cast<const float4*>(src + (size_t)m * D_K + t * 4);
  bf16x4 o = {(__bf16)v.x, (__bf16)v.y, (__bf16)v.z, (__bf16)v.w};
  *reinterpret_cast<bf16x4*>(dst + (size_t)m * D_K + t * 4) = o;
  float ss = v.x * v.x + v.y * v.y + v.z * v.z + v.w * v.w;
  ss += __shfl_xor(ss, 1);
  ss += __shfl_xor(ss, 2);
  ss += __shfl_xor(ss, 4);
  ss += __shfl_xor(ss, 8);
  ss += __shfl_xor(ss, 16);
  ss += __shfl_xor(ss, 32);
  __shared__ float ws4[4];
  const int w = t >> 6, l = t & 63;
  if (l == 0) ws4[w] = ss;
  __syncthreads();
  if (t == 0) sq[m] = ws4[0] + ws4[1] + ws4[2] + ws4[3];
}

// =================== round-1 fallback (proven) ===================
template <bool WS>
__global__ __launch_bounds__(256, 2) void fused_min(const float* __restrict__ embeds,
                                                    const float* __restrict__ centf,
                                                    const __bf16* __restrict__ cbf,
                                                    const float* __restrict__ csq,
                                                    float* __restrict__ out) {
  __shared__ __align__(16) char Ab[TM * 128];
  __shared__ __align__(16) char Bb[TN * 128];
  __shared__ float rowmin2[2][TM];
  __shared__ float sqrow[TM];
  __shared__ float colsq[TN];

  const int t = threadIdx.x;
  const int w = t >> 6;
  const int l = t & 63;
  const int wr = w >> 1, wc = w & 1;
  const int g = l >> 4, lr = l & 15;
  const long row0 = (long)blockIdx.x * TM;

  float runmin[4][4];
#pragma unroll
  for (int m = 0; m < 4; ++m)
#pragma unroll
    for (int r = 0; r < 4; ++r) runmin[m][r] = 3.0e38f;

  float sqpart[8];
#pragma unroll
  for (int c = 0; c < 8; ++c) sqpart[c] = 0.f;

  for (int nt = 0; nt < NT_TILES; ++nt) {
    const int col0 = nt * TN;
    f32x4 acc[4][4];
#pragma unroll
    for (int m = 0; m < 4; ++m)
#pragma unroll
      for (int n = 0; n < 4; ++n) acc[m][n] = (f32x4){0.f, 0.f, 0.f, 0.f};

    float cpart[8];
    if constexpr (!WS) {
#pragma unroll
      for (int c = 0; c < 8; ++c) cpart[c] = 0.f;
    }

    for (int kt = 0; kt < KT_STEPS; ++kt) {
      __syncthreads();
      if constexpr (WS) {
#pragma unroll
        for (int i = 0; i < 4; ++i) {
          const int s = (w * 4 + i) * 64 + l;
          const int col = s >> 3, sl = s & 7;
          const __bf16* src =
              cbf + (size_t)(col0 + col) * D_K + kt * BK + ((sl ^ (col & 7)) << 3);
          __builtin_amdgcn_global_load_lds(
              (const AS1 unsigned int*)(const void*)src,
              (AS3 unsigned int*)(void*)(Bb + (w * 4 + i) * 1024), 16, 0, 0);
        }
      } else {
#pragma unroll
        for (int c = 0; c < 8; ++c) {
          const int f = c * 256 + t;
          const int col = f >> 4, kq = f & 15;
          const float4 v = *reinterpret_cast<const float4*>(
              centf + (size_t)(col0 + col) * D_K + kt * BK + kq * 4);
          cpart[c] += v.x * v.x + v.y * v.y + v.z * v.z + v.w * v.w;
          bf16x4 o = {(__bf16)v.x, (__bf16)v.y, (__bf16)v.z, (__bf16)v.w};
          const int slot = kq >> 1;
          *reinterpret_cast<bf16x4*>(Bb + col * 128 + ((slot ^ (col & 7)) << 4) +
                                     (kq & 1) * 8) = o;
        }
      }
#pragma unroll
      for (int c = 0; c < 8; ++c) {
        const int f = c * 256 + t;
        const int row = f >> 4, kq = f & 15;
        const float4 v = *reinterpret_cast<const float4*>(
            embeds + (row0 + row) * (long)D_K + kt * BK + kq * 4);
        if (nt == 0) sqpart[c] += v.x * v.x + v.y * v.y + v.z * v.z + v.w * v.w;
        bf16x4 o = {(__bf16)v.x, (__bf16)v.y, (__bf16)v.z, (__bf16)v.w};
        const int slot = kq >> 1;
        *reinterpret_cast<bf16x4*>(Ab + row * 128 + ((slot ^ (row & 7)) << 4) +
                                   (kq & 1) * 8) = o;
      }
      __syncthreads();
#pragma unroll
      for (int ks = 0; ks < 2; ++ks) {
        bf16x8 af[4], bfr[4];
#pragma unroll
        for (int m = 0; m < 4; ++m) {
          const int row = wr * 64 + m * 16 + lr;
          const int slot = ks * 4 + g;
          af[m] = *reinterpret_cast<const bf16x8*>(Ab + row * 128 +
                                                   ((slot ^ (row & 7)) << 4));
        }
#pragma unroll
        for (int n = 0; n < 4; ++n) {
          const int col = wc * 64 + n * 16 + lr;
          const int slot = ks * 4 + g;
          bfr[n] = *reinterpret_cast<const bf16x8*>(Bb + col * 128 +
                                                    ((slot ^ (col & 7)) << 4));
        }
#pragma unroll
        for (int m = 0; m < 4; ++m)
#pragma unroll
          for (int n = 0; n < 4; ++n)
            acc[m][n] =
                __builtin_amdgcn_mfma_f32_16x16x32_bf16(af[m], bfr[n], acc[m][n], 0, 0, 0);
      }
    }

    if (nt == 0) {
#pragma unroll
      for (int c = 0; c < 8; ++c) {
        float ss = sqpart[c];
        ss += __shfl_xor(ss, 1);
        ss += __shfl_xor(ss, 2);
        ss += __shfl_xor(ss, 4);
        ss += __shfl_xor(ss, 8);
        if (lr == 0) sqrow[c * 16 + (w * 4 + g)] = ss;
      }
    }
    if constexpr (!WS) {
#pragma unroll
      for (int c = 0; c < 8; ++c) {
        float ss = cpart[c];
        ss += __shfl_xor(ss, 1);
        ss += __shfl_xor(ss, 2);
        ss += __shfl_xor(ss, 4);
        ss += __shfl_xor(ss, 8);
        if (lr == 0) colsq[c * 16 + (w * 4 + g)] = ss;
      }
      __syncthreads();
    }

#pragma unroll
    for (int n = 0; n < 4; ++n) {
      float cs;
      if constexpr (WS)
        cs = csq[col0 + wc * 64 + n * 16 + lr];
      else
        cs = colsq[wc * 64 + n * 16 + lr];
#pragma unroll
      for (int m = 0; m < 4; ++m)
#pragma unroll
        for (int r = 0; r < 4; ++r)
          runmin[m][r] = fminf(runmin[m][r], cs - 2.0f * acc[m][n][r]);
    }
  }

#pragma unroll
  for (int m = 0; m < 4; ++m)
#pragma unroll
    for (int r = 0; r < 4; ++r) {
      float v = runmin[m][r];
      v = fminf(v, __shfl_xor(v, 1));
      v = fminf(v, __shfl_xor(v, 2));
      v = fminf(v, __shfl_xor(v, 4));
      v = fminf(v, __shfl_xor(v, 8));
      runmin[m][r] = v;
    }
  if (lr == 0) {
#pragma unroll
    for (int m = 0; m < 4; ++m)
#pragma unroll
      for (int r = 0; r < 4; ++r)
        rowmin2[wc][wr * 64 + m * 16 + g * 4 + r] = runmin[m][r];
  }
  __syncthreads();
  if (t < TM) {
    const float v = fminf(rowmin2[0][t], rowmin2[1][t]);
    out[row0 + t] = sqrtf(fmaxf(sqrow[t] + v, 0.f));
  }
}

extern "C" void kernel_launch(void* const* d_in, const int* in_sizes, int n_in,
                              void* d_out, int out_size, void* d_ws, size_t ws_size,
                              hipStream_t stream) {
  const float* embeds = (const float*)d_in[0];
  const float* cent = (const float*)d_in[1];
  float* out = (float*)d_out;

  // ws layout for the fp8 fast path (~112 MiB)
  const size_t off_c8 = 0;
  const size_t off_csq = off_c8 + (size_t)M_CENT * D_K;             // 2 MiB
  const size_t off_e8 = off_csq + (size_t)M_CENT * 4;               // +8 KiB
  const size_t off_esq = off_e8 + (size_t)N_ROWS * D_K;             // +98 MiB
  const size_t off_pmin = off_esq + (size_t)N_ROWS * 4;             // +392 KiB
  const size_t need_full = off_pmin + (size_t)N_ROWS * NCT4 * 4;    // +6.1 MiB
  const size_t need_small = (size_t)M_CENT * D_K * 2 + (size_t)M_CENT * 4;

  if (ws_size >= need_full) {
    unsigned char* c8 = (unsigned char*)d_ws + off_c8;
    float* csq = (float*)((char*)d_ws + off_csq);
    unsigned char* e8 = (unsigned char*)d_ws + off_e8;
    float* esq = (float*)((char*)d_ws + off_esq);
    float* pmin = (float*)((char*)d_ws + off_pmin);
    rowsq_fp8pack<<<M_CENT, 256, 0, stream>>>(cent, c8, csq);
    rowsq_fp8pack<<<N_ROWS, 256, 0, stream>>>(embeds, e8, esq);
    gemm_min_mx<<<NBLK4, 256, 0, stream>>>(e8, c8, csq, pmin);
    final_min<<<N_ROWS / 256, 256, 0, stream>>>(esq, pmin, out);
  } else if (ws_size >= need_small) {
    __bf16* cbf = (__bf16*)d_ws;
    float* csq = (float*)((char*)d_ws + (size_t)M_CENT * D_K * 2);
    rowsq_bf16<<<M_CENT, 256, 0, stream>>>(cent, cbf, csq);
    fused_min<true><<<N_ROWS / TM, 256, 0, stream>>>(embeds, cent, cbf, csq, out);
  } else {
    fused_min<false><<<N_ROWS / TM, 256, 0, stream>>>(embeds, cent, nullptr, nullptr, out);
  }
}